// Round 7
// baseline (2216.380 us; speedup 1.0000x reference)
//
#include <hip/hip_runtime.h>
#include <stdint.h>

#define BATCH 8192
#define ADIM 128
#define HDIM 256
#define VDIM 64
#define NSTEP 20
#define TB 16
#define HSP 17   // h_s stride (floats): odd -> lane-distributed b32 reads conflict-free
#define ASP 20   // attr_s stride: rows stay 16B-aligned for b128 reads

typedef union { float4 v; float f[4]; } F4;

// ---------------- Threefry-2x32 (exactly JAX's lowering) ----------------
__device__ __forceinline__ uint32_t rotl32(uint32_t x, uint32_t d) {
  return (x << d) | (x >> (32u - d));
}
__device__ __forceinline__ void tf4(uint32_t& x0, uint32_t& x1, int r0, int r1, int r2, int r3) {
  x0 += x1; x1 = rotl32(x1, r0); x1 ^= x0;
  x0 += x1; x1 = rotl32(x1, r1); x1 ^= x0;
  x0 += x1; x1 = rotl32(x1, r2); x1 ^= x0;
  x0 += x1; x1 = rotl32(x1, r3); x1 ^= x0;
}
__device__ __forceinline__ void threefry2x32(uint32_t k0, uint32_t k1, uint32_t x0, uint32_t x1,
                                             uint32_t& o0, uint32_t& o1) {
  uint32_t k2 = k0 ^ k1 ^ 0x1BD11BDAu;
  x0 += k0; x1 += k1;
  tf4(x0, x1, 13, 15, 26, 6);  x0 += k1; x1 += k2 + 1u;
  tf4(x0, x1, 17, 29, 16, 24); x0 += k2; x1 += k0 + 2u;
  tf4(x0, x1, 13, 15, 26, 6);  x0 += k0; x1 += k1 + 3u;
  tf4(x0, x1, 17, 29, 16, 24); x0 += k1; x1 += k2 + 4u;
  tf4(x0, x1, 13, 15, 26, 6);  x0 += k2; x1 += k0 + 5u;
  o0 = x0; o1 = x1;
}

__device__ __forceinline__ float sigm(float x) { return 1.0f / (1.0f + expf(-x)); }

// wave-uniform broadcast of lane t's value -> SGPR (feeds v_fma scalar slot)
__device__ __forceinline__ float bcast(float x, int t) {
  return __int_as_float(__builtin_amdgcn_readlane(__float_as_int(x), t));
}

// ---------------- prep: repack weights, gate-interleaved per unit ----------------
// ws layout (floats): WhhT4[256][256][4] @0      (k, unit, gate)  1 MB
//                     WvT  [256][64]     @262144 (k, v)
//                     WaT  [128][256]    @278528 (k, unit)
//                     WihT4[64][256][4]  @311296 (v, unit, gate)
__global__ void prep_kernel(const float* __restrict__ Whh, const float* __restrict__ Wv,
                            const float* __restrict__ Wa, const float* __restrict__ Wih,
                            float* __restrict__ ws) {
  int n = blockIdx.x * blockDim.x + threadIdx.x;
  int stride = gridDim.x * blockDim.x;
  float* WhhT4 = ws;
  float* WvT   = ws + 262144;
  float* WaT   = ws + 278528;
  float* WihT4 = ws + 311296;
  for (int i = n; i < 256 * 1024; i += stride) {
    int k = i >> 10, rem = i & 1023, u = rem >> 2, g = rem & 3;
    WhhT4[i] = Whh[((g << 8) + u) * 256 + k];
  }
  for (int i = n; i < 256 * 64; i += stride) { int k = i >> 6, v = i & 63; WvT[i] = Wv[v * 256 + k]; }
  for (int i = n; i < 128 * 256; i += stride) { int k = i >> 8, u = i & 255; WaT[i] = Wa[u * 128 + k]; }
  for (int i = n; i < 64 * 1024; i += stride) {
    int v = i >> 10, rem = i & 1023, u = rem >> 2, g = rem & 3;
    WihT4[i] = Wih[((g << 8) + u) * 64 + v];
  }
}

// ---------------- main persistent kernel ----------------
// 512 blocks x 256 threads; block owns TB=16 samples for all 21 steps.
// Thread owns 2 units x 8 samples: wave w -> units [128*(w&1), +128)
// (u_a = lane, u_b = lane+64 within the half), sample half 8*(w>>1),
// slot rotation 4*(w&1) so this wave's 4 logit samples are slots 0..3
// (all register indices compile-time; dynamic indices only touch LDS).
// Rationale: broadcast count per k = slots/thread. R6 spent ~138 cyc/k on
// 16 v_readlane (~8.6 cyc each); this halves it to 8 while keeping 64
// gate FMAs/k/thread. Weights: 2 coalesced dwordx4 per k (32 B/lane).
// FMA values and k-order identical to R6 -> bit-exact.
__global__ __launch_bounds__(256, 2) void sender_main(
    const float* __restrict__ attr, const float* __restrict__ b_a,
    const float* __restrict__ b_ih, const float* __restrict__ b_hh,
    const float* __restrict__ b_v,
    const float* __restrict__ WhhT4, const float* __restrict__ WvT,
    const float* __restrict__ WaT, const float* __restrict__ WihT4,
    float* __restrict__ out) {
  __shared__ float h_s[HDIM][HSP];                    // h_s[unit][phys sample]
  __shared__ __align__(16) float attr_s[ADIM][ASP];   // attr_s[k][sample]
  __shared__ float slp_s[TB], plp_s[TB], ep_s[TB];
  __shared__ int ch_s[TB];

  const int tid = threadIdx.x;
  const int w = tid >> 6;         // wave id
  const int lane = tid & 63;
  const int half = w & 1;         // unit half
  const int sh = w >> 1;          // sample half
  const int u_a = (half << 7) + lane;   // first unit
  const int u_b = u_a + 64;             // second unit
  const int base = sh << 3;             // first phys sample of this thread's 8
  const int rot = half << 2;            // slot rotation: phys(s) = base + ((s+rot)&7)
  const int w4 = w << 2;                // first phys sample this wave samples
  const int b0 = blockIdx.x * TB;

  if (tid < TB) { slp_s[tid] = 0.0f; plp_s[tid] = 0.0f; ep_s[tid] = 1.0f; }

  // ---- stage attr tile, transposed to k-major ----
  {
    int r = tid >> 5;            // 0..7
    int cm = (tid & 31) << 2;    // 0,4,...,124
    #pragma unroll
    for (int pass = 0; pass < 2; ++pass) {
      int row = r + (pass << 3);
      F4 vv; vv.v = *(const float4*)&attr[(size_t)(b0 + row) * ADIM + cm];
      attr_s[cm + 0][row] = vv.f[0];
      attr_s[cm + 1][row] = vv.f[1];
      attr_s[cm + 2][row] = vv.f[2];
      attr_s[cm + 3][row] = vv.f[3];
    }
  }
  __syncthreads();

  // ---- h0 = attr @ W_a^T + b_a : acc[unit][phys p] (phys order; no rotation needed) ----
  {
    float acc[2][8];
    #pragma unroll
    for (int c = 0; c < 2; ++c)
      #pragma unroll
      for (int p = 0; p < 8; ++p) acc[c][p] = 0.0f;
    #pragma unroll 2
    for (int k = 0; k < ADIM; ++k) {
      F4 lo, hi;
      lo.v = *(const float4*)&attr_s[k][base];
      hi.v = *(const float4*)&attr_s[k][base + 4];
      float wa_a = WaT[(k << 8) + u_a];
      float wa_b = WaT[(k << 8) + u_b];
      #pragma unroll
      for (int p = 0; p < 8; ++p) {
        float av = (p < 4) ? lo.f[p] : hi.f[p - 4];
        acc[0][p] = fmaf(av, wa_a, acc[0][p]);
        acc[1][p] = fmaf(av, wa_b, acc[1][p]);
      }
    }
    float ba_a = b_a[u_a], ba_b = b_a[u_b];
    #pragma unroll
    for (int p = 0; p < 8; ++p) {
      h_s[u_a][base + p] = acc[0][p] + ba_a;
      h_s[u_b][base + p] = acc[1][p] + ba_b;
    }
  }
  __syncthreads();

  // persistent per-thread state: cell state per [unit][slot]
  float c_r[2][8];
  #pragma unroll
  for (int c = 0; c < 2; ++c)
    #pragma unroll
    for (int s = 0; s < 8; ++s) c_r[c][s] = 0.0f;

  float bga[4], bgb[4];  // b_ih + b_hh per gate, both units
  #pragma unroll
  for (int g = 0; g < 4; ++g) {
    bga[g] = b_ih[(g << 8) + u_a] + b_hh[(g << 8) + u_a];
    bgb[g] = b_ih[(g << 8) + u_b] + b_hh[(g << 8) + u_b];
  }
  const float bv = b_v[lane];

  // ---- initial LSTM step, x = 0 ----
  {
    float ga[2][8][4];  // [unit][slot][gate]
    #pragma unroll
    for (int c = 0; c < 2; ++c)
      #pragma unroll
      for (int s = 0; s < 8; ++s)
        #pragma unroll
        for (int g = 0; g < 4; ++g) ga[c][s][g] = 0.0f;
    #pragma unroll 1
    for (int kc = 0; kc < 16; ++kc) {
      const int k0 = kc << 4;
      const int kk = k0 + (lane & 15);
      float hch[8];
      #pragma unroll
      for (int s = 0; s < 8; ++s) hch[s] = h_s[kk][base + ((s + rot) & 7)];
      #pragma unroll
      for (int t = 0; t < 16; ++t) {
        const int k = k0 + t;
        F4 wa, wb;
        wa.v = *(const float4*)&WhhT4[(k << 10) + (u_a << 2)];
        wb.v = *(const float4*)&WhhT4[(k << 10) + (u_b << 2)];
        #pragma unroll
        for (int s = 0; s < 8; ++s) {
          float hb = bcast(hch[s], t);
          ga[0][s][0] = fmaf(hb, wa.f[0], ga[0][s][0]);
          ga[0][s][1] = fmaf(hb, wa.f[1], ga[0][s][1]);
          ga[0][s][2] = fmaf(hb, wa.f[2], ga[0][s][2]);
          ga[0][s][3] = fmaf(hb, wa.f[3], ga[0][s][3]);
          ga[1][s][0] = fmaf(hb, wb.f[0], ga[1][s][0]);
          ga[1][s][1] = fmaf(hb, wb.f[1], ga[1][s][1]);
          ga[1][s][2] = fmaf(hb, wb.f[2], ga[1][s][2]);
          ga[1][s][3] = fmaf(hb, wb.f[3], ga[1][s][3]);
        }
      }
    }
    __syncthreads();  // all reads of h_s done before overwrite
    #pragma unroll
    for (int s = 0; s < 8; ++s) {
      const int p = base + ((s + rot) & 7);
      {
        float gi = ga[0][s][0] + bga[0];
        float gf = ga[0][s][1] + bga[1];
        float gg = ga[0][s][2] + bga[2];
        float go = ga[0][s][3] + bga[3];
        float cn = sigm(gf) * c_r[0][s] + sigm(gi) * tanhf(gg);
        float hn = sigm(go) * tanhf(cn);
        c_r[0][s] = cn;
        h_s[u_a][p] = hn;
      }
      {
        float gi = ga[1][s][0] + bgb[0];
        float gf = ga[1][s][1] + bgb[1];
        float gg = ga[1][s][2] + bgb[2];
        float go = ga[1][s][3] + bgb[3];
        float cn = sigm(gf) * c_r[1][s] + sigm(gi) * tanhf(gg);
        float hn = sigm(go) * tanhf(cn);
        c_r[1][s] = cn;
        h_s[u_b][p] = hn;
      }
    }
    __syncthreads();
  }

  // ---- 20 sampled steps ----
  #pragma unroll 1
  for (int l = 0; l < NSTEP; ++l) {
    uint32_t kl0, kl1;
    threefry2x32(0u, 42u, 0u, (uint32_t)l, kl0, kl1);

    const bool last = (l == NSTEP - 1);
    float la[4] = {0.0f, 0.0f, 0.0f, 0.0f};  // logits for phys samples w4..w4+3 (slots 0..3)
    float ga[2][8][4];
    #pragma unroll
    for (int c = 0; c < 2; ++c)
      #pragma unroll
      for (int s = 0; s < 8; ++s)
        #pragma unroll
        for (int g = 0; g < 4; ++g) ga[c][s][g] = 0.0f;

    if (!last) {
      #pragma unroll 1
      for (int kc = 0; kc < 16; ++kc) {
        const int k0 = kc << 4;
        const int kk = k0 + (lane & 15);
        float hch[8];
        #pragma unroll
        for (int s = 0; s < 8; ++s) hch[s] = h_s[kk][base + ((s + rot) & 7)];
        #pragma unroll
        for (int t = 0; t < 16; ++t) {
          const int k = k0 + t;
          F4 wa, wb;
          wa.v = *(const float4*)&WhhT4[(k << 10) + (u_a << 2)];
          wb.v = *(const float4*)&WhhT4[(k << 10) + (u_b << 2)];
          float wvv = WvT[(k << 6) | lane];
          #pragma unroll
          for (int s = 0; s < 8; ++s) {
            float hb = bcast(hch[s], t);
            if (s < 4) la[s] = fmaf(hb, wvv, la[s]);  // slots 0..3 = phys w4..w4+3
            ga[0][s][0] = fmaf(hb, wa.f[0], ga[0][s][0]);
            ga[0][s][1] = fmaf(hb, wa.f[1], ga[0][s][1]);
            ga[0][s][2] = fmaf(hb, wa.f[2], ga[0][s][2]);
            ga[0][s][3] = fmaf(hb, wa.f[3], ga[0][s][3]);
            ga[1][s][0] = fmaf(hb, wb.f[0], ga[1][s][0]);
            ga[1][s][1] = fmaf(hb, wb.f[1], ga[1][s][1]);
            ga[1][s][2] = fmaf(hb, wb.f[2], ga[1][s][2]);
            ga[1][s][3] = fmaf(hb, wb.f[3], ga[1][s][3]);
          }
        }
      }
    } else {
      // logits only
      #pragma unroll 1
      for (int kc = 0; kc < 16; ++kc) {
        const int k0 = kc << 4;
        const int kk = k0 + (lane & 15);
        float hch[4];
        #pragma unroll
        for (int s = 0; s < 4; ++s) hch[s] = h_s[kk][base + ((s + rot) & 7)];
        #pragma unroll
        for (int t = 0; t < 16; ++t) {
          const int k = k0 + t;
          float wvv = WvT[(k << 6) | lane];
          #pragma unroll
          for (int s = 0; s < 4; ++s) la[s] = fmaf(bcast(hch[s], t), wvv, la[s]);
        }
      }
    }

    // ---- sampling: wave w handles phys samples w4..w4+3; lane holds logit[b][lane] ----
    #pragma unroll
    for (int db = 0; db < 4; ++db) {
      float x = la[db] + bv;  // logits = h@W_v^T + b_v
      float m = x;
      #pragma unroll
      for (int o = 32; o > 0; o >>= 1) m = fmaxf(m, __shfl_xor(m, o));
      float e = expf(x - m);
      float s = e;
      #pragma unroll
      for (int o = 32; o > 0; o >>= 1) s += __shfl_xor(s, o);
      float lse = logf(s);
      float logp = x - m - lse;
      float p = expf(logp);
      float pe = p * logp;
      #pragma unroll
      for (int o = 32; o > 0; o >>= 1) pe += __shfl_xor(pe, o);
      uint32_t idx = ((uint32_t)(b0 + w4 + db) << 6) | (uint32_t)lane;
      uint32_t r0, r1;
      threefry2x32(kl0, kl1, 0u, idx, r0, r1);
      uint32_t bits = r0 ^ r1;
      float f01 = __uint_as_float((bits >> 9) | 0x3f800000u) - 1.0f;
      const float TINY = 1.17549435e-38f;
      float uu2 = fmaxf(TINY, f01 + TINY);
      float gn = -logf(-logf(uu2));
      float y = gn + x;
      float by = y; int bi = lane;
      #pragma unroll
      for (int o = 32; o > 0; o >>= 1) {
        float oy = __shfl_xor(by, o);
        int oi = __shfl_xor(bi, o);
        if (oy > by || (oy == by && oi < bi)) { by = oy; bi = oi; }
      }
      float lp = __shfl(logp, bi, 64);
      if (lane == 0) {
        int bb = w4 + db;
        ch_s[bb] = bi;
        slp_s[bb] += lp;
        plp_s[bb] += pe;
        ep_s[bb] *= expf(lp);
        out[(size_t)(b0 + bb) * NSTEP + l] = (float)bi;
      }
    }

    if (!last) {
      __syncthreads();  // everyone finished reading h_s; ch_s visible
      #pragma unroll
      for (int s = 0; s < 8; ++s) {
        const int p = base + ((s + rot) & 7);
        const int ch = ch_s[p];
        F4 wia, wib;
        wia.v = *(const float4*)&WihT4[(ch << 10) + (u_a << 2)];
        wib.v = *(const float4*)&WihT4[(ch << 10) + (u_b << 2)];
        {
          float gi = ga[0][s][0] + wia.f[0] + bga[0];
          float gf = ga[0][s][1] + wia.f[1] + bga[1];
          float gg = ga[0][s][2] + wia.f[2] + bga[2];
          float go = ga[0][s][3] + wia.f[3] + bga[3];
          float cn = sigm(gf) * c_r[0][s] + sigm(gi) * tanhf(gg);
          float hn = sigm(go) * tanhf(cn);
          c_r[0][s] = cn;
          h_s[u_a][p] = hn;
        }
        {
          float gi = ga[1][s][0] + wib.f[0] + bgb[0];
          float gf = ga[1][s][1] + wib.f[1] + bgb[1];
          float gg = ga[1][s][2] + wib.f[2] + bgb[2];
          float go = ga[1][s][3] + wib.f[3] + bgb[3];
          float cn = sigm(gf) * c_r[1][s] + sigm(gi) * tanhf(gg);
          float hn = sigm(go) * tanhf(cn);
          c_r[1][s] = cn;
          h_s[u_b][p] = hn;
        }
      }
      __syncthreads();
    }
  }

  __syncthreads();
  if (tid < TB) {
    int bb = b0 + tid;
    out[(size_t)BATCH * NSTEP + bb]             = slp_s[tid];
    out[(size_t)BATCH * NSTEP + BATCH + bb]     = plp_s[tid];
    out[(size_t)BATCH * NSTEP + 2 * BATCH + bb] = ep_s[tid];
  }
}

extern "C" void kernel_launch(void* const* d_in, const int* in_sizes, int n_in,
                              void* d_out, int out_size, void* d_ws, size_t ws_size,
                              hipStream_t stream) {
  // setup_inputs order:
  // 0 attrVector [8192,128], 1 W_a [256,128], 2 b_a [256], 3 W_ih [1024,64],
  // 4 W_hh [1024,256], 5 b_ih [1024], 6 b_hh [1024], 7 W_v [64,256], 8 b_v [64]
  const float* attr = (const float*)d_in[0];
  const float* W_a  = (const float*)d_in[1];
  const float* b_a  = (const float*)d_in[2];
  const float* W_ih = (const float*)d_in[3];
  const float* W_hh = (const float*)d_in[4];
  const float* b_ih = (const float*)d_in[5];
  const float* b_hh = (const float*)d_in[6];
  const float* W_v  = (const float*)d_in[7];
  const float* b_v  = (const float*)d_in[8];
  float* ws = (float*)d_ws;

  prep_kernel<<<256, 256, 0, stream>>>(W_hh, W_v, W_a, W_ih, ws);
  sender_main<<<BATCH / TB, 256, 0, stream>>>(
      attr, b_a, b_ih, b_hh, b_v,
      ws, ws + 262144, ws + 278528, ws + 311296,
      (float*)d_out);
}

// Round 8
// 2201.531 us; speedup vs baseline: 1.0067x; 1.0067x over previous
//
#include <hip/hip_runtime.h>
#include <stdint.h>

#define BATCH 8192
#define ADIM 128
#define HDIM 256
#define VDIM 64
#define NSTEP 20
#define TB 16
#define HSP 17   // h_s/c_s stride (floats): odd -> lane-distributed b32 reads conflict-free
#define ASP 20   // attr_s stride: rows stay 16B-aligned for b128 reads

typedef union { float4 v; float f[4]; } F4;

// ---------------- Threefry-2x32 (exactly JAX's lowering) ----------------
__device__ __forceinline__ uint32_t rotl32(uint32_t x, uint32_t d) {
  return (x << d) | (x >> (32u - d));
}
__device__ __forceinline__ void tf4(uint32_t& x0, uint32_t& x1, int r0, int r1, int r2, int r3) {
  x0 += x1; x1 = rotl32(x1, r0); x1 ^= x0;
  x0 += x1; x1 = rotl32(x1, r1); x1 ^= x0;
  x0 += x1; x1 = rotl32(x1, r2); x1 ^= x0;
  x0 += x1; x1 = rotl32(x1, r3); x1 ^= x0;
}
__device__ __forceinline__ void threefry2x32(uint32_t k0, uint32_t k1, uint32_t x0, uint32_t x1,
                                             uint32_t& o0, uint32_t& o1) {
  uint32_t k2 = k0 ^ k1 ^ 0x1BD11BDAu;
  x0 += k0; x1 += k1;
  tf4(x0, x1, 13, 15, 26, 6);  x0 += k1; x1 += k2 + 1u;
  tf4(x0, x1, 17, 29, 16, 24); x0 += k2; x1 += k0 + 2u;
  tf4(x0, x1, 13, 15, 26, 6);  x0 += k0; x1 += k1 + 3u;
  tf4(x0, x1, 17, 29, 16, 24); x0 += k1; x1 += k2 + 4u;
  tf4(x0, x1, 13, 15, 26, 6);  x0 += k2; x1 += k0 + 5u;
  o0 = x0; o1 = x1;
}

__device__ __forceinline__ float sigm(float x) { return 1.0f / (1.0f + expf(-x)); }

// wave-uniform broadcast of lane t's value -> SGPR (feeds v_fma scalar slot)
__device__ __forceinline__ float bcast(float x, int t) {
  return __int_as_float(__builtin_amdgcn_readlane(__float_as_int(x), t));
}

// ---------------- prep: repack weights, gate-interleaved per unit ----------------
// ws layout (floats): WhhT4[256][256][4] @0      (k, unit, gate)  1 MB
//                     WvT  [256][64]     @262144 (k, v)
//                     WaT  [128][256]    @278528 (k, unit)
//                     WihT4[64][256][4]  @311296 (v, unit, gate)
//                     bsum4[256][4]      @376832 (unit, gate) = b_ih+b_hh
__global__ void prep_kernel(const float* __restrict__ Whh, const float* __restrict__ Wv,
                            const float* __restrict__ Wa, const float* __restrict__ Wih,
                            const float* __restrict__ bih, const float* __restrict__ bhh,
                            float* __restrict__ ws) {
  int n = blockIdx.x * blockDim.x + threadIdx.x;
  int stride = gridDim.x * blockDim.x;
  float* WhhT4 = ws;
  float* WvT   = ws + 262144;
  float* WaT   = ws + 278528;
  float* WihT4 = ws + 311296;
  float* bsum4 = ws + 376832;
  for (int i = n; i < 256 * 1024; i += stride) {
    int k = i >> 10, rem = i & 1023, u = rem >> 2, g = rem & 3;
    WhhT4[i] = Whh[((g << 8) + u) * 256 + k];
  }
  for (int i = n; i < 256 * 64; i += stride) { int k = i >> 6, v = i & 63; WvT[i] = Wv[v * 256 + k]; }
  for (int i = n; i < 128 * 256; i += stride) { int k = i >> 8, u = i & 255; WaT[i] = Wa[u * 128 + k]; }
  for (int i = n; i < 64 * 1024; i += stride) {
    int v = i >> 10, rem = i & 1023, u = rem >> 2, g = rem & 3;
    WihT4[i] = Wih[((g << 8) + u) * 64 + v];
  }
  for (int i = n; i < 1024; i += stride) {
    int u = i >> 2, g = i & 3;
    bsum4[i] = bih[(g << 8) + u] + bhh[(g << 8) + u];
  }
}

// ---------------- main persistent kernel ----------------
// 512 blocks x 256 threads; block owns TB=16 samples for all 21 steps.
// Thread owns 2 units x 8 samples (wave w: units [128*(w&1),+128), sample
// half 8*(w>>1); slot rotation 4*(w&1) keeps this wave's 4 logit samples at
// compile-time slots 0..3). 8 v_readlane per k (vs R6's 16) with 64 gate
// FMAs -- the R7 idea, minus R7's spill: cell state lives in LDS (c_s) and
// gate biases are preloaded per-step from ws (bsum4), so the k-loop's live
// set is ~100 VGPR and fits the 128-VGPR allocation without scratch.
__global__ __launch_bounds__(256, 2) void sender_main(
    const float* __restrict__ attr, const float* __restrict__ b_a,
    const float* __restrict__ b_v,
    const float* __restrict__ WhhT4, const float* __restrict__ WvT,
    const float* __restrict__ WaT, const float* __restrict__ WihT4,
    const float* __restrict__ bsum4,
    float* __restrict__ out) {
  __shared__ float h_s[HDIM][HSP];                    // h_s[unit][phys sample]
  __shared__ float c_s[HDIM][HSP];                    // cell state, same layout
  __shared__ __align__(16) float attr_s[ADIM][ASP];   // attr_s[k][sample]
  __shared__ float slp_s[TB], plp_s[TB], ep_s[TB];
  __shared__ int ch_s[TB];

  const int tid = threadIdx.x;
  const int w = tid >> 6;         // wave id
  const int lane = tid & 63;
  const int half = w & 1;         // unit half
  const int sh = w >> 1;          // sample half
  const int u_a = (half << 7) + lane;   // first unit
  const int u_b = u_a + 64;             // second unit
  const int base = sh << 3;             // first phys sample of this thread's 8
  const int rot = half << 2;            // slot rotation: phys(s) = base + ((s+rot)&7)
  const int w4 = w << 2;                // first phys sample this wave samples
  const int b0 = blockIdx.x * TB;

  if (tid < TB) { slp_s[tid] = 0.0f; plp_s[tid] = 0.0f; ep_s[tid] = 1.0f; }

  // ---- stage attr tile, transposed to k-major ----
  {
    int r = tid >> 5;            // 0..7
    int cm = (tid & 31) << 2;    // 0,4,...,124
    #pragma unroll
    for (int pass = 0; pass < 2; ++pass) {
      int row = r + (pass << 3);
      F4 vv; vv.v = *(const float4*)&attr[(size_t)(b0 + row) * ADIM + cm];
      attr_s[cm + 0][row] = vv.f[0];
      attr_s[cm + 1][row] = vv.f[1];
      attr_s[cm + 2][row] = vv.f[2];
      attr_s[cm + 3][row] = vv.f[3];
    }
  }
  __syncthreads();

  // ---- h0 = attr @ W_a^T + b_a : acc[unit][phys p] ----
  {
    float acc[2][8];
    #pragma unroll
    for (int c = 0; c < 2; ++c)
      #pragma unroll
      for (int p = 0; p < 8; ++p) acc[c][p] = 0.0f;
    #pragma unroll 2
    for (int k = 0; k < ADIM; ++k) {
      F4 lo, hi;
      lo.v = *(const float4*)&attr_s[k][base];
      hi.v = *(const float4*)&attr_s[k][base + 4];
      float wa_a = WaT[(k << 8) + u_a];
      float wa_b = WaT[(k << 8) + u_b];
      #pragma unroll
      for (int p = 0; p < 8; ++p) {
        float av = (p < 4) ? lo.f[p] : hi.f[p - 4];
        acc[0][p] = fmaf(av, wa_a, acc[0][p]);
        acc[1][p] = fmaf(av, wa_b, acc[1][p]);
      }
    }
    float ba_a = b_a[u_a], ba_b = b_a[u_b];
    #pragma unroll
    for (int p = 0; p < 8; ++p) {
      h_s[u_a][base + p] = acc[0][p] + ba_a;
      h_s[u_b][base + p] = acc[1][p] + ba_b;
    }
  }
  __syncthreads();

  const float bv = b_v[lane];

  // ---- initial LSTM step, x = 0, c_prev = 0 ----
  {
    float ga[2][8][4];  // [unit][slot][gate]
    #pragma unroll
    for (int c = 0; c < 2; ++c)
      #pragma unroll
      for (int s = 0; s < 8; ++s)
        #pragma unroll
        for (int g = 0; g < 4; ++g) ga[c][s][g] = 0.0f;
    #pragma unroll 1
    for (int kc = 0; kc < 16; ++kc) {
      const int k0 = kc << 4;
      const int kk = k0 + (lane & 15);
      float hch[8];
      #pragma unroll
      for (int s = 0; s < 8; ++s) hch[s] = h_s[kk][base + ((s + rot) & 7)];
      #pragma unroll
      for (int t = 0; t < 16; ++t) {
        const int k = k0 + t;
        F4 wa, wb;
        wa.v = *(const float4*)&WhhT4[(k << 10) + (u_a << 2)];
        wb.v = *(const float4*)&WhhT4[(k << 10) + (u_b << 2)];
        #pragma unroll
        for (int s = 0; s < 8; ++s) {
          float hb = bcast(hch[s], t);
          ga[0][s][0] = fmaf(hb, wa.f[0], ga[0][s][0]);
          ga[0][s][1] = fmaf(hb, wa.f[1], ga[0][s][1]);
          ga[0][s][2] = fmaf(hb, wa.f[2], ga[0][s][2]);
          ga[0][s][3] = fmaf(hb, wa.f[3], ga[0][s][3]);
          ga[1][s][0] = fmaf(hb, wb.f[0], ga[1][s][0]);
          ga[1][s][1] = fmaf(hb, wb.f[1], ga[1][s][1]);
          ga[1][s][2] = fmaf(hb, wb.f[2], ga[1][s][2]);
          ga[1][s][3] = fmaf(hb, wb.f[3], ga[1][s][3]);
        }
      }
    }
    __syncthreads();  // all reads of h_s done before overwrite
    F4 bsa, bsb;
    bsa.v = *(const float4*)&bsum4[u_a << 2];
    bsb.v = *(const float4*)&bsum4[u_b << 2];
    #pragma unroll
    for (int s = 0; s < 8; ++s) {
      const int p = base + ((s + rot) & 7);
      {
        float gi = ga[0][s][0] + bsa.f[0];
        float gf = ga[0][s][1] + bsa.f[1];
        float gg = ga[0][s][2] + bsa.f[2];
        float go = ga[0][s][3] + bsa.f[3];
        float cn = sigm(gf) * 0.0f + sigm(gi) * tanhf(gg);
        h_s[u_a][p] = sigm(go) * tanhf(cn);
        c_s[u_a][p] = cn;
      }
      {
        float gi = ga[1][s][0] + bsb.f[0];
        float gf = ga[1][s][1] + bsb.f[1];
        float gg = ga[1][s][2] + bsb.f[2];
        float go = ga[1][s][3] + bsb.f[3];
        float cn = sigm(gf) * 0.0f + sigm(gi) * tanhf(gg);
        h_s[u_b][p] = sigm(go) * tanhf(cn);
        c_s[u_b][p] = cn;
      }
    }
    __syncthreads();
  }

  // ---- 20 sampled steps ----
  #pragma unroll 1
  for (int l = 0; l < NSTEP; ++l) {
    uint32_t kl0, kl1;
    threefry2x32(0u, 42u, 0u, (uint32_t)l, kl0, kl1);

    const bool last = (l == NSTEP - 1);
    float la[4] = {0.0f, 0.0f, 0.0f, 0.0f};  // logits for phys samples w4..w4+3 (slots 0..3)
    float ga[2][8][4];
    #pragma unroll
    for (int c = 0; c < 2; ++c)
      #pragma unroll
      for (int s = 0; s < 8; ++s)
        #pragma unroll
        for (int g = 0; g < 4; ++g) ga[c][s][g] = 0.0f;

    if (!last) {
      #pragma unroll 1
      for (int kc = 0; kc < 16; ++kc) {
        const int k0 = kc << 4;
        const int kk = k0 + (lane & 15);
        float hch[8];
        #pragma unroll
        for (int s = 0; s < 8; ++s) hch[s] = h_s[kk][base + ((s + rot) & 7)];
        #pragma unroll
        for (int t = 0; t < 16; ++t) {
          const int k = k0 + t;
          F4 wa, wb;
          wa.v = *(const float4*)&WhhT4[(k << 10) + (u_a << 2)];
          wb.v = *(const float4*)&WhhT4[(k << 10) + (u_b << 2)];
          float wvv = WvT[(k << 6) | lane];
          #pragma unroll
          for (int s = 0; s < 8; ++s) {
            float hb = bcast(hch[s], t);
            if (s < 4) la[s] = fmaf(hb, wvv, la[s]);  // slots 0..3 = phys w4..w4+3
            ga[0][s][0] = fmaf(hb, wa.f[0], ga[0][s][0]);
            ga[0][s][1] = fmaf(hb, wa.f[1], ga[0][s][1]);
            ga[0][s][2] = fmaf(hb, wa.f[2], ga[0][s][2]);
            ga[0][s][3] = fmaf(hb, wa.f[3], ga[0][s][3]);
            ga[1][s][0] = fmaf(hb, wb.f[0], ga[1][s][0]);
            ga[1][s][1] = fmaf(hb, wb.f[1], ga[1][s][1]);
            ga[1][s][2] = fmaf(hb, wb.f[2], ga[1][s][2]);
            ga[1][s][3] = fmaf(hb, wb.f[3], ga[1][s][3]);
          }
        }
      }
    } else {
      // logits only
      #pragma unroll 1
      for (int kc = 0; kc < 16; ++kc) {
        const int k0 = kc << 4;
        const int kk = k0 + (lane & 15);
        float hch[4];
        #pragma unroll
        for (int s = 0; s < 4; ++s) hch[s] = h_s[kk][base + ((s + rot) & 7)];
        #pragma unroll
        for (int t = 0; t < 16; ++t) {
          const int k = k0 + t;
          float wvv = WvT[(k << 6) | lane];
          #pragma unroll
          for (int s = 0; s < 4; ++s) la[s] = fmaf(bcast(hch[s], t), wvv, la[s]);
        }
      }
    }

    // ---- sampling: wave w handles phys samples w4..w4+3; lane holds logit[b][lane] ----
    #pragma unroll
    for (int db = 0; db < 4; ++db) {
      float x = la[db] + bv;  // logits = h@W_v^T + b_v
      float m = x;
      #pragma unroll
      for (int o = 32; o > 0; o >>= 1) m = fmaxf(m, __shfl_xor(m, o));
      float e = expf(x - m);
      float s = e;
      #pragma unroll
      for (int o = 32; o > 0; o >>= 1) s += __shfl_xor(s, o);
      float lse = logf(s);
      float logp = x - m - lse;
      float p = expf(logp);
      float pe = p * logp;
      #pragma unroll
      for (int o = 32; o > 0; o >>= 1) pe += __shfl_xor(pe, o);
      uint32_t idx = ((uint32_t)(b0 + w4 + db) << 6) | (uint32_t)lane;
      uint32_t r0, r1;
      threefry2x32(kl0, kl1, 0u, idx, r0, r1);
      uint32_t bits = r0 ^ r1;
      float f01 = __uint_as_float((bits >> 9) | 0x3f800000u) - 1.0f;
      const float TINY = 1.17549435e-38f;
      float uu2 = fmaxf(TINY, f01 + TINY);
      float gn = -logf(-logf(uu2));
      float y = gn + x;
      float by = y; int bi = lane;
      #pragma unroll
      for (int o = 32; o > 0; o >>= 1) {
        float oy = __shfl_xor(by, o);
        int oi = __shfl_xor(bi, o);
        if (oy > by || (oy == by && oi < bi)) { by = oy; bi = oi; }
      }
      float lp = __shfl(logp, bi, 64);
      if (lane == 0) {
        int bb = w4 + db;
        ch_s[bb] = bi;
        slp_s[bb] += lp;
        plp_s[bb] += pe;
        ep_s[bb] *= expf(lp);
        out[(size_t)(b0 + bb) * NSTEP + l] = (float)bi;
      }
    }

    if (!last) {
      __syncthreads();  // everyone finished reading h_s; ch_s visible
      F4 bsa, bsb;
      bsa.v = *(const float4*)&bsum4[u_a << 2];
      bsb.v = *(const float4*)&bsum4[u_b << 2];
      #pragma unroll
      for (int s = 0; s < 8; ++s) {
        const int p = base + ((s + rot) & 7);
        const int ch = ch_s[p];
        F4 wia, wib;
        wia.v = *(const float4*)&WihT4[(ch << 10) + (u_a << 2)];
        wib.v = *(const float4*)&WihT4[(ch << 10) + (u_b << 2)];
        {
          float gi = ga[0][s][0] + wia.f[0] + bsa.f[0];
          float gf = ga[0][s][1] + wia.f[1] + bsa.f[1];
          float gg = ga[0][s][2] + wia.f[2] + bsa.f[2];
          float go = ga[0][s][3] + wia.f[3] + bsa.f[3];
          float cn = sigm(gf) * c_s[u_a][p] + sigm(gi) * tanhf(gg);
          h_s[u_a][p] = sigm(go) * tanhf(cn);
          c_s[u_a][p] = cn;
        }
        {
          float gi = ga[1][s][0] + wib.f[0] + bsb.f[0];
          float gf = ga[1][s][1] + wib.f[1] + bsb.f[1];
          float gg = ga[1][s][2] + wib.f[2] + bsb.f[2];
          float go = ga[1][s][3] + wib.f[3] + bsb.f[3];
          float cn = sigm(gf) * c_s[u_b][p] + sigm(gi) * tanhf(gg);
          h_s[u_b][p] = sigm(go) * tanhf(cn);
          c_s[u_b][p] = cn;
        }
      }
      __syncthreads();
    }
  }

  __syncthreads();
  if (tid < TB) {
    int bb = b0 + tid;
    out[(size_t)BATCH * NSTEP + bb]             = slp_s[tid];
    out[(size_t)BATCH * NSTEP + BATCH + bb]     = plp_s[tid];
    out[(size_t)BATCH * NSTEP + 2 * BATCH + bb] = ep_s[tid];
  }
}

extern "C" void kernel_launch(void* const* d_in, const int* in_sizes, int n_in,
                              void* d_out, int out_size, void* d_ws, size_t ws_size,
                              hipStream_t stream) {
  // setup_inputs order:
  // 0 attrVector [8192,128], 1 W_a [256,128], 2 b_a [256], 3 W_ih [1024,64],
  // 4 W_hh [1024,256], 5 b_ih [1024], 6 b_hh [1024], 7 W_v [64,256], 8 b_v [64]
  const float* attr = (const float*)d_in[0];
  const float* W_a  = (const float*)d_in[1];
  const float* b_a  = (const float*)d_in[2];
  const float* W_ih = (const float*)d_in[3];
  const float* W_hh = (const float*)d_in[4];
  const float* b_ih = (const float*)d_in[5];
  const float* b_hh = (const float*)d_in[6];
  const float* W_v  = (const float*)d_in[7];
  const float* b_v  = (const float*)d_in[8];
  float* ws = (float*)d_ws;

  prep_kernel<<<256, 256, 0, stream>>>(W_hh, W_v, W_a, W_ih, b_ih, b_hh, ws);
  sender_main<<<BATCH / TB, 256, 0, stream>>>(
      attr, b_a, b_v,
      ws, ws + 262144, ws + 278528, ws + 311296, ws + 376832,
      (float*)d_out);
}

// Round 9
// 1518.400 us; speedup vs baseline: 1.4597x; 1.4499x over previous
//
#include <hip/hip_runtime.h>
#include <stdint.h>

#define BATCH 8192
#define ADIM 128
#define HDIM 256
#define VDIM 64
#define NSTEP 20
#define TB 8     // samples per block -> 1024 blocks -> 4 blocks/CU, 16 waves/CU
#define HSP 9    // h_s stride: odd -> 16-lane-distributed b32 reads conflict-free
#define ASP 12   // attr_s stride: 48B rows keep b128 reads 16B-aligned

typedef union { float4 v; float f[4]; } F4;

// ---------------- Threefry-2x32 (exactly JAX's lowering) ----------------
__device__ __forceinline__ uint32_t rotl32(uint32_t x, uint32_t d) {
  return (x << d) | (x >> (32u - d));
}
__device__ __forceinline__ void tf4(uint32_t& x0, uint32_t& x1, int r0, int r1, int r2, int r3) {
  x0 += x1; x1 = rotl32(x1, r0); x1 ^= x0;
  x0 += x1; x1 = rotl32(x1, r1); x1 ^= x0;
  x0 += x1; x1 = rotl32(x1, r2); x1 ^= x0;
  x0 += x1; x1 = rotl32(x1, r3); x1 ^= x0;
}
__device__ __forceinline__ void threefry2x32(uint32_t k0, uint32_t k1, uint32_t x0, uint32_t x1,
                                             uint32_t& o0, uint32_t& o1) {
  uint32_t k2 = k0 ^ k1 ^ 0x1BD11BDAu;
  x0 += k0; x1 += k1;
  tf4(x0, x1, 13, 15, 26, 6);  x0 += k1; x1 += k2 + 1u;
  tf4(x0, x1, 17, 29, 16, 24); x0 += k2; x1 += k0 + 2u;
  tf4(x0, x1, 13, 15, 26, 6);  x0 += k0; x1 += k1 + 3u;
  tf4(x0, x1, 17, 29, 16, 24); x0 += k1; x1 += k2 + 4u;
  tf4(x0, x1, 13, 15, 26, 6);  x0 += k2; x1 += k0 + 5u;
  o0 = x0; o1 = x1;
}

__device__ __forceinline__ float sigm(float x) { return 1.0f / (1.0f + expf(-x)); }

// wave-uniform broadcast of lane t's value -> SGPR (feeds v_fma scalar slot)
__device__ __forceinline__ float bcast(float x, int t) {
  return __int_as_float(__builtin_amdgcn_readlane(__float_as_int(x), t));
}

// ---------------- prep: repack weights, gate-interleaved per unit ----------------
// ws layout (floats): WhhT4[256][256][4] @0      (k, unit, gate)  1 MB
//                     WvT  [256][64]     @262144 (k, v)
//                     WaT  [128][256]    @278528 (k, unit)
//                     WihT4[64][256][4]  @311296 (v, unit, gate)
__global__ void prep_kernel(const float* __restrict__ Whh, const float* __restrict__ Wv,
                            const float* __restrict__ Wa, const float* __restrict__ Wih,
                            float* __restrict__ ws) {
  int n = blockIdx.x * blockDim.x + threadIdx.x;
  int stride = gridDim.x * blockDim.x;
  float* WhhT4 = ws;
  float* WvT   = ws + 262144;
  float* WaT   = ws + 278528;
  float* WihT4 = ws + 311296;
  for (int i = n; i < 256 * 1024; i += stride) {
    int k = i >> 10, rem = i & 1023, u = rem >> 2, g = rem & 3;
    WhhT4[i] = Whh[((g << 8) + u) * 256 + k];
  }
  for (int i = n; i < 256 * 64; i += stride) { int k = i >> 6, v = i & 63; WvT[i] = Wv[v * 256 + k]; }
  for (int i = n; i < 128 * 256; i += stride) { int k = i >> 8, u = i & 255; WaT[i] = Wa[u * 128 + k]; }
  for (int i = n; i < 64 * 1024; i += stride) {
    int v = i >> 10, rem = i & 1023, u = rem >> 2, g = rem & 3;
    WihT4[i] = Wih[((g << 8) + u) * 64 + v];
  }
}

// ---------------- main persistent kernel ----------------
// 1024 blocks x 256 threads; block owns TB=8 samples for all 21 steps.
// Lane = unit (u = 64w+lane); thread computes 4 gates x 8 samples for its
// unit. Same verified R6 dataflow (coalesced 16B/lane weight dwordx4,
// chunked lane-distribution + v_readlane h-broadcast), but 4 blocks/CU
// (16 waves/CU, 4 waves/SIMD) to hide the readlane->SGPR->FMA and memory
// latencies that R6's 2 waves/SIMD could not (R8 refuted the issue-cost
// model; residue is stall time).
// Slot rotation by 2w: this wave's 2 logit samples live at compile-time
// slots 0..1 (all register indices static; dynamic indices only touch LDS).
__global__ __launch_bounds__(256, 4) void sender_main(
    const float* __restrict__ attr, const float* __restrict__ b_a,
    const float* __restrict__ b_ih, const float* __restrict__ b_hh,
    const float* __restrict__ b_v,
    const float* __restrict__ WhhT4, const float* __restrict__ WvT,
    const float* __restrict__ WaT, const float* __restrict__ WihT4,
    float* __restrict__ out) {
  __shared__ float h_s[HDIM][HSP];                    // h_s[unit][phys sample]
  __shared__ __align__(16) float attr_s[ADIM][ASP];   // attr_s[k][sample]
  __shared__ float slp_s[TB], plp_s[TB], ep_s[TB];
  __shared__ int ch_s[TB];

  const int tid = threadIdx.x;
  const int w = tid >> 6;         // wave id
  const int lane = tid & 63;
  const int u = (w << 6) + lane;  // unit owned by this thread
  const int rot = w << 1;         // slot rotation: phys(s) = (s + 2w) & 7
  const int w2 = w << 1;          // first phys sample this wave samples
  const int b0 = blockIdx.x * TB;

  if (tid < TB) { slp_s[tid] = 0.0f; plp_s[tid] = 0.0f; ep_s[tid] = 1.0f; }

  // ---- stage attr tile, transposed to k-major (8 rows x 128 cols) ----
  {
    int r = tid >> 5;            // 0..7
    int cm = (tid & 31) << 2;    // 0,4,...,124
    F4 vv; vv.v = *(const float4*)&attr[(size_t)(b0 + r) * ADIM + cm];
    attr_s[cm + 0][r] = vv.f[0];
    attr_s[cm + 1][r] = vv.f[1];
    attr_s[cm + 2][r] = vv.f[2];
    attr_s[cm + 3][r] = vv.f[3];
  }
  __syncthreads();

  // ---- h0 = attr @ W_a^T + b_a : acc[phys p] for this thread's unit ----
  {
    float acc[8];
    #pragma unroll
    for (int p = 0; p < 8; ++p) acc[p] = 0.0f;
    #pragma unroll 2
    for (int k = 0; k < ADIM; ++k) {
      F4 lo, hi;
      lo.v = *(const float4*)&attr_s[k][0];
      hi.v = *(const float4*)&attr_s[k][4];
      float wa = WaT[(k << 8) + u];
      #pragma unroll
      for (int j = 0; j < 4; ++j) {
        acc[j]     = fmaf(lo.f[j], wa, acc[j]);
        acc[4 + j] = fmaf(hi.f[j], wa, acc[4 + j]);
      }
    }
    float ba = b_a[u];
    #pragma unroll
    for (int p = 0; p < 8; ++p) h_s[u][p] = acc[p] + ba;
  }
  __syncthreads();

  // persistent per-thread state: cell state per slot (slot s = phys (s+2w)&7)
  float c_r[8];
  #pragma unroll
  for (int s = 0; s < 8; ++s) c_r[s] = 0.0f;

  float bg[4];  // b_ih + b_hh per gate for this unit
  #pragma unroll
  for (int g = 0; g < 4; ++g) bg[g] = b_ih[(g << 8) + u] + b_hh[(g << 8) + u];
  const float bv = b_v[lane];

  // ---- initial LSTM step, x = 0, c_prev = 0 ----
  {
    float ga[8][4];  // [slot][gate]
    #pragma unroll
    for (int s = 0; s < 8; ++s)
      #pragma unroll
      for (int g = 0; g < 4; ++g) ga[s][g] = 0.0f;
    #pragma unroll 1
    for (int kc = 0; kc < 16; ++kc) {
      const int k0 = kc << 4;
      const int kk = k0 + (lane & 15);
      float hch[8];
      #pragma unroll
      for (int s = 0; s < 8; ++s) hch[s] = h_s[kk][(s + rot) & 7];
      #pragma unroll
      for (int t = 0; t < 16; ++t) {
        const int k = k0 + t;
        F4 wv4; wv4.v = *(const float4*)&WhhT4[(k << 10) + (u << 2)];
        #pragma unroll
        for (int s = 0; s < 8; ++s) {
          float hb = bcast(hch[s], t);
          ga[s][0] = fmaf(hb, wv4.f[0], ga[s][0]);
          ga[s][1] = fmaf(hb, wv4.f[1], ga[s][1]);
          ga[s][2] = fmaf(hb, wv4.f[2], ga[s][2]);
          ga[s][3] = fmaf(hb, wv4.f[3], ga[s][3]);
        }
      }
    }
    __syncthreads();  // all reads of h_s done before overwrite
    #pragma unroll
    for (int s = 0; s < 8; ++s) {
      const int p = (s + rot) & 7;
      float gi = ga[s][0] + bg[0];
      float gf = ga[s][1] + bg[1];
      float gg = ga[s][2] + bg[2];
      float go = ga[s][3] + bg[3];
      float cn = sigm(gf) * c_r[s] + sigm(gi) * tanhf(gg);
      float hn = sigm(go) * tanhf(cn);
      c_r[s] = cn;
      h_s[u][p] = hn;
    }
    __syncthreads();
  }

  // ---- 20 sampled steps ----
  #pragma unroll 1
  for (int l = 0; l < NSTEP; ++l) {
    uint32_t kl0, kl1;
    threefry2x32(0u, 42u, 0u, (uint32_t)l, kl0, kl1);

    const bool last = (l == NSTEP - 1);
    float la[2] = {0.0f, 0.0f};  // logits for phys samples 2w..2w+1 (slots 0..1)
    float ga[8][4];
    #pragma unroll
    for (int s = 0; s < 8; ++s)
      #pragma unroll
      for (int g = 0; g < 4; ++g) ga[s][g] = 0.0f;

    if (!last) {
      #pragma unroll 1
      for (int kc = 0; kc < 16; ++kc) {
        const int k0 = kc << 4;
        const int kk = k0 + (lane & 15);
        float hch[8];
        #pragma unroll
        for (int s = 0; s < 8; ++s) hch[s] = h_s[kk][(s + rot) & 7];
        #pragma unroll
        for (int t = 0; t < 16; ++t) {
          const int k = k0 + t;
          F4 wv4; wv4.v = *(const float4*)&WhhT4[(k << 10) + (u << 2)];
          float wvv = WvT[(k << 6) | lane];
          #pragma unroll
          for (int s = 0; s < 8; ++s) {
            float hb = bcast(hch[s], t);
            if (s < 2) la[s] = fmaf(hb, wvv, la[s]);  // slots 0..1 = phys 2w..2w+1
            ga[s][0] = fmaf(hb, wv4.f[0], ga[s][0]);
            ga[s][1] = fmaf(hb, wv4.f[1], ga[s][1]);
            ga[s][2] = fmaf(hb, wv4.f[2], ga[s][2]);
            ga[s][3] = fmaf(hb, wv4.f[3], ga[s][3]);
          }
        }
      }
    } else {
      // logits only
      #pragma unroll 1
      for (int kc = 0; kc < 16; ++kc) {
        const int k0 = kc << 4;
        const int kk = k0 + (lane & 15);
        float hch[2];
        #pragma unroll
        for (int s = 0; s < 2; ++s) hch[s] = h_s[kk][(s + rot) & 7];
        #pragma unroll
        for (int t = 0; t < 16; ++t) {
          const int k = k0 + t;
          float wvv = WvT[(k << 6) | lane];
          #pragma unroll
          for (int s = 0; s < 2; ++s) la[s] = fmaf(bcast(hch[s], t), wvv, la[s]);
        }
      }
    }

    // ---- sampling: wave w handles phys samples 2w..2w+1; lane holds logit[b][lane] ----
    #pragma unroll
    for (int db = 0; db < 2; ++db) {
      float x = la[db] + bv;  // logits = h@W_v^T + b_v
      float m = x;
      #pragma unroll
      for (int o = 32; o > 0; o >>= 1) m = fmaxf(m, __shfl_xor(m, o));
      float e = expf(x - m);
      float s = e;
      #pragma unroll
      for (int o = 32; o > 0; o >>= 1) s += __shfl_xor(s, o);
      float lse = logf(s);
      float logp = x - m - lse;
      float p = expf(logp);
      float pe = p * logp;
      #pragma unroll
      for (int o = 32; o > 0; o >>= 1) pe += __shfl_xor(pe, o);
      uint32_t idx = ((uint32_t)(b0 + w2 + db) << 6) | (uint32_t)lane;
      uint32_t r0, r1;
      threefry2x32(kl0, kl1, 0u, idx, r0, r1);
      uint32_t bits = r0 ^ r1;
      float f01 = __uint_as_float((bits >> 9) | 0x3f800000u) - 1.0f;
      const float TINY = 1.17549435e-38f;
      float uu2 = fmaxf(TINY, f01 + TINY);
      float gn = -logf(-logf(uu2));
      float y = gn + x;
      float by = y; int bi = lane;
      #pragma unroll
      for (int o = 32; o > 0; o >>= 1) {
        float oy = __shfl_xor(by, o);
        int oi = __shfl_xor(bi, o);
        if (oy > by || (oy == by && oi < bi)) { by = oy; bi = oi; }
      }
      float lp = __shfl(logp, bi, 64);
      if (lane == 0) {
        int bb = w2 + db;
        ch_s[bb] = bi;
        slp_s[bb] += lp;
        plp_s[bb] += pe;
        ep_s[bb] *= expf(lp);
        out[(size_t)(b0 + bb) * NSTEP + l] = (float)bi;
      }
    }

    if (!last) {
      __syncthreads();  // everyone finished reading h_s; ch_s visible
      #pragma unroll
      for (int s = 0; s < 8; ++s) {
        const int p = (s + rot) & 7;
        F4 wi; wi.v = *(const float4*)&WihT4[(ch_s[p] << 10) + (u << 2)];
        float gi = ga[s][0] + wi.f[0] + bg[0];
        float gf = ga[s][1] + wi.f[1] + bg[1];
        float gg = ga[s][2] + wi.f[2] + bg[2];
        float go = ga[s][3] + wi.f[3] + bg[3];
        float cn = sigm(gf) * c_r[s] + sigm(gi) * tanhf(gg);
        float hn = sigm(go) * tanhf(cn);
        c_r[s] = cn;
        h_s[u][p] = hn;
      }
      __syncthreads();
    }
  }

  __syncthreads();
  if (tid < TB) {
    int bb = b0 + tid;
    out[(size_t)BATCH * NSTEP + bb]             = slp_s[tid];
    out[(size_t)BATCH * NSTEP + BATCH + bb]     = plp_s[tid];
    out[(size_t)BATCH * NSTEP + 2 * BATCH + bb] = ep_s[tid];
  }
}

extern "C" void kernel_launch(void* const* d_in, const int* in_sizes, int n_in,
                              void* d_out, int out_size, void* d_ws, size_t ws_size,
                              hipStream_t stream) {
  // setup_inputs order:
  // 0 attrVector [8192,128], 1 W_a [256,128], 2 b_a [256], 3 W_ih [1024,64],
  // 4 W_hh [1024,256], 5 b_ih [1024], 6 b_hh [1024], 7 W_v [64,256], 8 b_v [64]
  const float* attr = (const float*)d_in[0];
  const float* W_a  = (const float*)d_in[1];
  const float* b_a  = (const float*)d_in[2];
  const float* W_ih = (const float*)d_in[3];
  const float* W_hh = (const float*)d_in[4];
  const float* b_ih = (const float*)d_in[5];
  const float* b_hh = (const float*)d_in[6];
  const float* W_v  = (const float*)d_in[7];
  const float* b_v  = (const float*)d_in[8];
  float* ws = (float*)d_ws;

  prep_kernel<<<256, 256, 0, stream>>>(W_hh, W_v, W_a, W_ih, ws);
  sender_main<<<BATCH / TB, 256, 0, stream>>>(
      attr, b_a, b_ih, b_hh, b_v,
      ws, ws + 262144, ws + 278528, ws + 311296,
      (float*)d_out);
}

// Round 10
// 1445.143 us; speedup vs baseline: 1.5337x; 1.0507x over previous
//
#include <hip/hip_runtime.h>
#include <stdint.h>

#define BATCH 8192
#define ADIM 128
#define HDIM 256
#define VDIM 64
#define NSTEP 20
#define TB 16
#define HSP 17   // h_s stride (floats): odd -> lane-distributed b32 reads conflict-free
#define ASP 20   // attr_s stride: rows stay 16B-aligned for b128 reads

typedef union { float4 v; float f[4]; } F4;
typedef float v2f __attribute__((ext_vector_type(2)));

// ---------------- Threefry-2x32 (exactly JAX's lowering) ----------------
__device__ __forceinline__ uint32_t rotl32(uint32_t x, uint32_t d) {
  return (x << d) | (x >> (32u - d));
}
__device__ __forceinline__ void tf4(uint32_t& x0, uint32_t& x1, int r0, int r1, int r2, int r3) {
  x0 += x1; x1 = rotl32(x1, r0); x1 ^= x0;
  x0 += x1; x1 = rotl32(x1, r1); x1 ^= x0;
  x0 += x1; x1 = rotl32(x1, r2); x1 ^= x0;
  x0 += x1; x1 = rotl32(x1, r3); x1 ^= x0;
}
__device__ __forceinline__ void threefry2x32(uint32_t k0, uint32_t k1, uint32_t x0, uint32_t x1,
                                             uint32_t& o0, uint32_t& o1) {
  uint32_t k2 = k0 ^ k1 ^ 0x1BD11BDAu;
  x0 += k0; x1 += k1;
  tf4(x0, x1, 13, 15, 26, 6);  x0 += k1; x1 += k2 + 1u;
  tf4(x0, x1, 17, 29, 16, 24); x0 += k2; x1 += k0 + 2u;
  tf4(x0, x1, 13, 15, 26, 6);  x0 += k0; x1 += k1 + 3u;
  tf4(x0, x1, 17, 29, 16, 24); x0 += k1; x1 += k2 + 4u;
  tf4(x0, x1, 13, 15, 26, 6);  x0 += k2; x1 += k0 + 5u;
  o0 = x0; o1 = x1;
}

__device__ __forceinline__ float sigm(float x) { return 1.0f / (1.0f + expf(-x)); }

// wave-uniform broadcast of lane t's value -> SGPR (feeds v_fma scalar slot)
__device__ __forceinline__ float bcast(float x, int t) {
  return __int_as_float(__builtin_amdgcn_readlane(__float_as_int(x), t));
}

// ---------------- prep: repack weights, gate-interleaved per unit ----------------
// ws layout (floats): WhhT4[256][256][4] @0      (k, unit, gate)  1 MB
//                     WvT  [256][64]     @262144 (k, v)
//                     WaT  [128][256]    @278528 (k, unit)
//                     WihT4[64][256][4]  @311296 (v, unit, gate)
__global__ void prep_kernel(const float* __restrict__ Whh, const float* __restrict__ Wv,
                            const float* __restrict__ Wa, const float* __restrict__ Wih,
                            float* __restrict__ ws) {
  int n = blockIdx.x * blockDim.x + threadIdx.x;
  int stride = gridDim.x * blockDim.x;
  float* WhhT4 = ws;
  float* WvT   = ws + 262144;
  float* WaT   = ws + 278528;
  float* WihT4 = ws + 311296;
  for (int i = n; i < 256 * 1024; i += stride) {
    int k = i >> 10, rem = i & 1023, u = rem >> 2, g = rem & 3;
    WhhT4[i] = Whh[((g << 8) + u) * 256 + k];
  }
  for (int i = n; i < 256 * 64; i += stride) { int k = i >> 6, v = i & 63; WvT[i] = Wv[v * 256 + k]; }
  for (int i = n; i < 128 * 256; i += stride) { int k = i >> 8, u = i & 255; WaT[i] = Wa[u * 128 + k]; }
  for (int i = n; i < 64 * 1024; i += stride) {
    int v = i >> 10, rem = i & 1023, u = rem >> 2, g = rem & 3;
    WihT4[i] = Wih[((g << 8) + u) * 64 + v];
  }
}

// ---------------- main persistent kernel ----------------
// R6 shell (TB=16, lane=unit, 16 slots/thread, coalesced 16B/lane weight
// dwordx4, chunked lane-distribution + v_readlane h-broadcast, 128 VGPR,
// no spill) + PACKED fp32 FMA: gates (0,1) and (2,3) are adjacent in the
// weight quad, so each slot's 4 gate FMAs become 2 v_pk_fma_f32 with the
// wave-uniform hb splat into both halves. Per-element IEEE-identical,
// k-chain order unchanged -> bit-exact. ~30% fewer VALU issue cycles/k.
__global__ __launch_bounds__(256, 2) void sender_main(
    const float* __restrict__ attr, const float* __restrict__ b_a,
    const float* __restrict__ b_ih, const float* __restrict__ b_hh,
    const float* __restrict__ b_v,
    const float* __restrict__ WhhT4, const float* __restrict__ WvT,
    const float* __restrict__ WaT, const float* __restrict__ WihT4,
    float* __restrict__ out) {
  __shared__ float h_s[HDIM][HSP];                    // h_s[unit][phys sample]
  __shared__ __align__(16) float attr_s[ADIM][ASP];   // attr_s[k][sample]
  __shared__ float slp_s[TB], plp_s[TB], ep_s[TB];
  __shared__ int ch_s[TB];

  const int tid = threadIdx.x;
  const int w = tid >> 6;         // wave id
  const int lane = tid & 63;
  const int u = (w << 6) + lane;  // unit owned by this thread
  const int w4 = w << 2;          // first phys sample this wave samples; slot rot
  const int b0 = blockIdx.x * TB;

  if (tid < TB) { slp_s[tid] = 0.0f; plp_s[tid] = 0.0f; ep_s[tid] = 1.0f; }

  // ---- stage attr tile, transposed to k-major ----
  {
    int r = tid >> 5;            // 0..7
    int cm = (tid & 31) << 2;    // 0,4,...,124
    #pragma unroll
    for (int pass = 0; pass < 2; ++pass) {
      int row = r + (pass << 3);
      F4 vv; vv.v = *(const float4*)&attr[(size_t)(b0 + row) * ADIM + cm];
      attr_s[cm + 0][row] = vv.f[0];
      attr_s[cm + 1][row] = vv.f[1];
      attr_s[cm + 2][row] = vv.f[2];
      attr_s[cm + 3][row] = vv.f[3];
    }
  }
  __syncthreads();

  // ---- h0 = attr @ W_a^T + b_a : acc[phys sample] for this thread's unit ----
  {
    float acc[16];
    #pragma unroll
    for (int s = 0; s < 16; ++s) acc[s] = 0.0f;
    #pragma unroll 2
    for (int k = 0; k < ADIM; ++k) {
      F4 a0, a1, a2, a3;
      a0.v = *(const float4*)&attr_s[k][0];
      a1.v = *(const float4*)&attr_s[k][4];
      a2.v = *(const float4*)&attr_s[k][8];
      a3.v = *(const float4*)&attr_s[k][12];
      float wa = WaT[(k << 8) + u];
      #pragma unroll
      for (int j = 0; j < 4; ++j) {
        acc[j]      = fmaf(a0.f[j], wa, acc[j]);
        acc[4 + j]  = fmaf(a1.f[j], wa, acc[4 + j]);
        acc[8 + j]  = fmaf(a2.f[j], wa, acc[8 + j]);
        acc[12 + j] = fmaf(a3.f[j], wa, acc[12 + j]);
      }
    }
    float ba = b_a[u];
    #pragma unroll
    for (int s = 0; s < 16; ++s) h_s[u][s] = acc[s] + ba;
  }
  __syncthreads();

  // persistent per-thread state: cell state, slot s = phys sample (s+w4)&15
  float c_r[16];
  #pragma unroll
  for (int s = 0; s < 16; ++s) c_r[s] = 0.0f;

  float bg[4];  // b_ih + b_hh per gate for this unit
  #pragma unroll
  for (int g = 0; g < 4; ++g) bg[g] = b_ih[(g << 8) + u] + b_hh[(g << 8) + u];
  const float bv = b_v[lane];

  // ---- initial LSTM step, x = 0 ----
  {
    v2f ga01[16], ga23[16];  // [slot] x gate-pairs (0,1) and (2,3)
    #pragma unroll
    for (int s = 0; s < 16; ++s) { ga01[s] = (v2f)(0.0f); ga23[s] = (v2f)(0.0f); }
    #pragma unroll 1
    for (int kc = 0; kc < 16; ++kc) {
      const int k0 = kc << 4;
      const int kk = k0 + (lane & 15);
      float hch[16];
      #pragma unroll
      for (int s = 0; s < 16; ++s) hch[s] = h_s[kk][(s + w4) & 15];
      #pragma unroll
      for (int t = 0; t < 16; ++t) {
        const int k = k0 + t;
        F4 wv4; wv4.v = *(const float4*)&WhhT4[(k << 10) + (u << 2)];
        v2f w01 = {wv4.f[0], wv4.f[1]};
        v2f w23 = {wv4.f[2], wv4.f[3]};
        #pragma unroll
        for (int s = 0; s < 16; ++s) {
          float hb = bcast(hch[s], t);
          v2f hbv = {hb, hb};
          ga01[s] = __builtin_elementwise_fma(hbv, w01, ga01[s]);
          ga23[s] = __builtin_elementwise_fma(hbv, w23, ga23[s]);
        }
      }
    }
    __syncthreads();  // all reads of h_s done before overwrite
    float hn[16];
    #pragma unroll
    for (int s = 0; s < 16; ++s) {
      float gi = ga01[s][0] + bg[0];
      float gf = ga01[s][1] + bg[1];
      float gg = ga23[s][0] + bg[2];
      float go = ga23[s][1] + bg[3];
      float cn = sigm(gf) * c_r[s] + sigm(gi) * tanhf(gg);
      hn[s] = sigm(go) * tanhf(cn);
      c_r[s] = cn;
    }
    #pragma unroll
    for (int s = 0; s < 16; ++s) h_s[u][(s + w4) & 15] = hn[s];
    __syncthreads();
  }

  // ---- 20 sampled steps ----
  #pragma unroll 1
  for (int l = 0; l < NSTEP; ++l) {
    uint32_t kl0, kl1;
    threefry2x32(0u, 42u, 0u, (uint32_t)l, kl0, kl1);

    const bool last = (l == NSTEP - 1);
    float la[4] = {0.0f, 0.0f, 0.0f, 0.0f};  // logits for phys samples w4..w4+3 (slots 0..3)
    v2f ga01[16], ga23[16];
    #pragma unroll
    for (int s = 0; s < 16; ++s) { ga01[s] = (v2f)(0.0f); ga23[s] = (v2f)(0.0f); }

    if (!last) {
      #pragma unroll 1
      for (int kc = 0; kc < 16; ++kc) {
        const int k0 = kc << 4;
        const int kk = k0 + (lane & 15);
        float hch[16];
        #pragma unroll
        for (int s = 0; s < 16; ++s) hch[s] = h_s[kk][(s + w4) & 15];
        #pragma unroll
        for (int t = 0; t < 16; ++t) {
          const int k = k0 + t;
          F4 wv4; wv4.v = *(const float4*)&WhhT4[(k << 10) + (u << 2)];
          v2f w01 = {wv4.f[0], wv4.f[1]};
          v2f w23 = {wv4.f[2], wv4.f[3]};
          float wvv = WvT[(k << 6) | lane];
          #pragma unroll
          for (int s = 0; s < 16; ++s) {
            float hb = bcast(hch[s], t);
            v2f hbv = {hb, hb};
            if (s < 4) la[s] = fmaf(hb, wvv, la[s]);  // slots 0..3 = phys w4..w4+3
            ga01[s] = __builtin_elementwise_fma(hbv, w01, ga01[s]);
            ga23[s] = __builtin_elementwise_fma(hbv, w23, ga23[s]);
          }
        }
      }
    } else {
      // logits only
      #pragma unroll 1
      for (int kc = 0; kc < 16; ++kc) {
        const int k0 = kc << 4;
        const int kk = k0 + (lane & 15);
        float hch[4];
        #pragma unroll
        for (int s = 0; s < 4; ++s) hch[s] = h_s[kk][(s + w4) & 15];
        #pragma unroll
        for (int t = 0; t < 16; ++t) {
          const int k = k0 + t;
          float wvv = WvT[(k << 6) | lane];
          #pragma unroll
          for (int s = 0; s < 4; ++s) la[s] = fmaf(bcast(hch[s], t), wvv, la[s]);
        }
      }
    }

    // ---- sampling: wave w handles phys samples w4..w4+3; lane holds logit[b][lane] ----
    #pragma unroll
    for (int db = 0; db < 4; ++db) {
      float x = la[db] + bv;  // logits = h@W_v^T + b_v
      float m = x;
      #pragma unroll
      for (int o = 32; o > 0; o >>= 1) m = fmaxf(m, __shfl_xor(m, o));
      float e = expf(x - m);
      float s = e;
      #pragma unroll
      for (int o = 32; o > 0; o >>= 1) s += __shfl_xor(s, o);
      float lse = logf(s);
      float logp = x - m - lse;
      float p = expf(logp);
      float pe = p * logp;
      #pragma unroll
      for (int o = 32; o > 0; o >>= 1) pe += __shfl_xor(pe, o);
      uint32_t idx = ((uint32_t)(b0 + w4 + db) << 6) | (uint32_t)lane;
      uint32_t r0, r1;
      threefry2x32(kl0, kl1, 0u, idx, r0, r1);
      uint32_t bits = r0 ^ r1;
      float f01 = __uint_as_float((bits >> 9) | 0x3f800000u) - 1.0f;
      const float TINY = 1.17549435e-38f;
      float uu2 = fmaxf(TINY, f01 + TINY);
      float gn = -logf(-logf(uu2));
      float y = gn + x;
      float by = y; int bi = lane;
      #pragma unroll
      for (int o = 32; o > 0; o >>= 1) {
        float oy = __shfl_xor(by, o);
        int oi = __shfl_xor(bi, o);
        if (oy > by || (oy == by && oi < bi)) { by = oy; bi = oi; }
      }
      float lp = __shfl(logp, bi, 64);
      if (lane == 0) {
        int bb = w4 + db;
        ch_s[bb] = bi;
        slp_s[bb] += lp;
        plp_s[bb] += pe;
        ep_s[bb] *= expf(lp);
        out[(size_t)(b0 + bb) * NSTEP + l] = (float)bi;
      }
    }

    if (!last) {
      __syncthreads();  // everyone finished reading h_s; ch_s visible
      float hn[16];
      #pragma unroll
      for (int s = 0; s < 16; ++s) {
        const int sp = (s + w4) & 15;  // physical sample for this slot
        F4 wi; wi.v = *(const float4*)&WihT4[(ch_s[sp] << 10) + (u << 2)];
        float gi = ga01[s][0] + wi.f[0] + bg[0];
        float gf = ga01[s][1] + wi.f[1] + bg[1];
        float gg = ga23[s][0] + wi.f[2] + bg[2];
        float go = ga23[s][1] + wi.f[3] + bg[3];
        float cn = sigm(gf) * c_r[s] + sigm(gi) * tanhf(gg);
        hn[s] = sigm(go) * tanhf(cn);
        c_r[s] = cn;
      }
      #pragma unroll
      for (int s = 0; s < 16; ++s) h_s[u][(s + w4) & 15] = hn[s];
      __syncthreads();
    }
  }

  __syncthreads();
  if (tid < TB) {
    int bb = b0 + tid;
    out[(size_t)BATCH * NSTEP + bb]             = slp_s[tid];
    out[(size_t)BATCH * NSTEP + BATCH + bb]     = plp_s[tid];
    out[(size_t)BATCH * NSTEP + 2 * BATCH + bb] = ep_s[tid];
  }
}

extern "C" void kernel_launch(void* const* d_in, const int* in_sizes, int n_in,
                              void* d_out, int out_size, void* d_ws, size_t ws_size,
                              hipStream_t stream) {
  // setup_inputs order:
  // 0 attrVector [8192,128], 1 W_a [256,128], 2 b_a [256], 3 W_ih [1024,64],
  // 4 W_hh [1024,256], 5 b_ih [1024], 6 b_hh [1024], 7 W_v [64,256], 8 b_v [64]
  const float* attr = (const float*)d_in[0];
  const float* W_a  = (const float*)d_in[1];
  const float* b_a  = (const float*)d_in[2];
  const float* W_ih = (const float*)d_in[3];
  const float* W_hh = (const float*)d_in[4];
  const float* b_ih = (const float*)d_in[5];
  const float* b_hh = (const float*)d_in[6];
  const float* W_v  = (const float*)d_in[7];
  const float* b_v  = (const float*)d_in[8];
  float* ws = (float*)d_ws;

  prep_kernel<<<256, 256, 0, stream>>>(W_hh, W_v, W_a, W_ih, ws);
  sender_main<<<BATCH / TB, 256, 0, stream>>>(
      attr, b_a, b_ih, b_hh, b_v,
      ws, ws + 262144, ws + 278528, ws + 311296,
      (float*)d_out);
}